// Round 5
// baseline (334.810 us; speedup 1.0000x reference)
//
#include <hip/hip_runtime.h>
#include <math.h>

#define B_ 4096
#define D_ 512
#define G_ 128
#define N_ (G_*G_)        // 16384
#define NTP 128           // number of 128-wide n tiles (partials per row)
#define THR_ 0.95f
#define IMAX_ 0x7FFFFFFF

typedef float f32x4 __attribute__((ext_vector_type(4)));
typedef _Float16 half8 __attribute__((ext_vector_type(8)));

// ---------------- split fp32 -> f16 hi only ----------------
__global__ __launch_bounds__(256) void split_hi_kernel(const float* __restrict__ src,
                                                       _Float16* __restrict__ hi, int n4) {
    int i = blockIdx.x * 256 + threadIdx.x;
    if (i >= n4) return;
    float4 v = ((const float4*)src)[i];
    float vv[4] = {v.x, v.y, v.z, v.w};
    union { _Float16 h[4]; uint64_t u64; } H;
    #pragma unroll
    for (int j = 0; j < 4; j++) H.h[j] = (_Float16)vv[j];
    ((uint64_t*)hi)[i] = H.u64;
}

// ---------------- fused W split(hi) + wnorm; 4 rows per 256-thread block ----------------
__global__ __launch_bounds__(256) void prep_w_kernel(const float* __restrict__ W,
                                                     _Float16* __restrict__ hi,
                                                     float* __restrict__ wnorm) {
    int n = blockIdx.x * 4 + (threadIdx.x >> 6);
    int t = threadIdx.x & 63;
    const float* row = W + (size_t)n * D_;
    float4 a = ((const float4*)row)[t];
    float4 b = ((const float4*)row)[t + 64];
    float av[4] = {a.x, a.y, a.z, a.w}, bv[4] = {b.x, b.y, b.z, b.w};
    union { _Float16 h[4]; uint64_t u64; } Ha, Hb;
    #pragma unroll
    for (int j = 0; j < 4; j++) { Ha.h[j] = (_Float16)av[j]; Hb.h[j] = (_Float16)bv[j]; }
    ((uint64_t*)(hi + (size_t)n * D_))[t]       = Ha.u64;
    ((uint64_t*)(hi + (size_t)n * D_ + 256))[t] = Hb.u64;
    float s = a.x*a.x + a.y*a.y + a.z*a.z + a.w*a.w
            + b.x*b.x + b.y*b.y + b.z*b.z + b.w*b.w;
    #pragma unroll
    for (int off = 32; off > 0; off >>= 1) s += __shfl_down(s, off, 64);
    if (t == 0) wnorm[n] = s;
}

// ---------------- packed (value,index) helpers for argmin ----------------
__device__ __forceinline__ unsigned long long packmin(float v, int n) {
    unsigned u = __float_as_uint(v);
    u ^= (u & 0x80000000u) ? 0xFFFFFFFFu : 0x80000000u;
    return ((unsigned long long)u << 32) | (unsigned)n;
}
__device__ __forceinline__ void unpackmin(unsigned long long pkt, float* v, int* n) {
    unsigned u = (unsigned)(pkt >> 32);
    u = (u & 0x80000000u) ? (u ^ 0x80000000u) : ~u;
    *v = __uint_as_float(u);
    *n = (int)(unsigned)pkt;
}

// ---------------- MFMA score GEMM: 128x128 tile, 4 waves, 2 blocks/CU ----------------
// score = wnorm[n] - 2 * dot_f16(x, w)  (x_norm added per-row later; argmin-invariant).
//
// Round-4 post-mortem: 256x256/8-wave/128KB-LDS = 1 block/CU, barrier-lockstepped phases
// -> LDS pipe (~2260cy/tile/CU) and MFMA pipe (~2483cy) strictly serialize -> 21.6% MfmaUtil.
// This version: 64KB LDS -> 2 blocks/CU (cross-block pipe overlap), and a single-phase
// schedule with DOUBLE-BUFFERED FRAGMENTS: ds_reads for tile t+1 are issued BEFORE the
// MFMA cluster of tile t and drain under it (waited only at next iter's top).
// Per iter: {lgkm0+bar (WAR: all reads of buf[t&1] done) -> stage t+2 -> vmcnt(8)+bar
// (tile t+1 landed) -> 16 ds_read frags(t+1) -> 32 MFMA on frags(t)}.  2 barriers/tile.
// Tail: iter6 vmcnt(0); iter7 MFMA only.  K-order identical to round 4 -> bit-exact.
// LDS slot-XOR swizzle via pre-swizzled GLOBAL source (linear gload_lds dest) + swizzled reads.

#define PH_WAIT_(N) asm volatile("s_waitcnt vmcnt(" #N ")" ::: "memory")
#define PH_WAIT(N) PH_WAIT_(N)
#define WAITLGKM0 asm volatile("s_waitcnt lgkmcnt(0)" ::: "memory")
#define SBAR __builtin_amdgcn_s_barrier()
#define SCHED0 __builtin_amdgcn_sched_barrier(0)
#define PRIO1 __builtin_amdgcn_s_setprio(1)
#define PRIO0 __builtin_amdgcn_s_setprio(0)

// stage tile TT (A 16KB + B 16KB) into buf[TT&1]; 8 gload_lds x 16B per thread
#define STAGE_T(TT) do { \
    const int bo_ = ((TT) & 1) << 15; \
    _Pragma("unroll") for (int j = 0; j < 4; j++) \
        __builtin_amdgcn_global_load_lds( \
            (const __attribute__((address_space(1))) void*)(srcA + (TT) * 64 + j * (32 * D_)), \
            (__attribute__((address_space(3))) void*)(smem + bo_ + ldsst + j * 4096), 16, 0, 0); \
    _Pragma("unroll") for (int j = 0; j < 4; j++) \
        __builtin_amdgcn_global_load_lds( \
            (const __attribute__((address_space(1))) void*)(srcB + (TT) * 64 + j * (32 * D_)), \
            (__attribute__((address_space(3))) void*)(smem + bo_ + 16384 + ldsst + j * 4096), 16, 0, 0); \
} while (0)

// read the 16 fragment b128s of tile TT into frag set (AF, BF)
#define LOADFRAGS(TT, AF, BF) do { \
    const int bo_ = ((TT) & 1) << 15; \
    _Pragma("unroll") for (int mi = 0; mi < 4; mi++) { \
        AF[mi][0] = *(const half8*)(smem + bo_ + sA + mi * 2048 + swz0); \
        AF[mi][1] = *(const half8*)(smem + bo_ + sA + mi * 2048 + swz1); } \
    _Pragma("unroll") for (int ni = 0; ni < 4; ni++) { \
        BF[ni][0] = *(const half8*)(smem + bo_ + 16384 + sB + ni * 2048 + swz0); \
        BF[ni][1] = *(const half8*)(smem + bo_ + 16384 + sB + ni * 2048 + swz1); } \
} while (0)

#define DOMFMA(AF, BF) do { \
    SCHED0; PRIO1; \
    _Pragma("unroll") for (int mi = 0; mi < 4; mi++) \
      _Pragma("unroll") for (int ni = 0; ni < 4; ni++) { \
        acc[mi][ni] = __builtin_amdgcn_mfma_f32_16x16x32_f16(AF[mi][0], BF[ni][0], acc[mi][ni], 0, 0, 0); \
        acc[mi][ni] = __builtin_amdgcn_mfma_f32_16x16x32_f16(AF[mi][1], BF[ni][1], acc[mi][ni], 0, 0, 0); } \
    PRIO0; SCHED0; \
} while (0)

// FC = frags of tile TAU (ready), FN = frag set to fill with tile TAU+1
#define ITER(TAU, FCA, FCB, FNA, FNB, DO_STAGE, VMN) do { \
    WAITLGKM0; SCHED0; SBAR; \
    if (DO_STAGE) STAGE_T((TAU) + 2); \
    PH_WAIT(VMN); SBAR; \
    LOADFRAGS((TAU) + 1, FNA, FNB); \
    DOMFMA(FCA, FCB); \
} while (0)

__global__ __launch_bounds__(256, 2) void score_mfma_kernel(
    const _Float16* __restrict__ Ah, const _Float16* __restrict__ Wh,
    const float* __restrict__ wnorm,
    const int* __restrict__ labels, const int* __restrict__ clabels,
    float* __restrict__ pminv, int* __restrict__ pmini,
    float* __restrict__ pcminv, int* __restrict__ pcmini)
{
    __shared__ __align__(16) char smem[65536];  // buf0: A@0 B@16K; buf1: A@32K B@48K

    const int tid  = threadIdx.x;
    const int lane = tid & 63;
    const int wave = tid >> 6;
    const int wm = wave >> 1, wn = wave & 1;     // 2x2 wave grid; 64x64 per wave
    const int c = lane & 15, quad = lane >> 4;

    // XCD-chunked swizzle: 4096 blocks; per XCD a 16-ntile chunk (2MB W, L2-resident)
    const int o = blockIdx.x;
    const int xcd = o & 7, idx = o >> 3;
    const int ntile = (xcd << 4) | (idx & 15);
    const int mtile = idx >> 4;                  // 0..31
    const int m0 = mtile * 128, n0 = ntile * 128;

    // staging per-thread constants (pre-swizzled global source, linear LDS dest)
    const int rl = tid >> 3, sl = tid & 7;       // row 0..31 (+j*32), 16B slot
    const int ssl = sl ^ (rl & 7);               // swizzled source slot
    const _Float16* srcA = Ah + (size_t)(m0 + rl) * D_ + (ssl << 3);
    const _Float16* srcB = Wh + (size_t)(n0 + rl) * D_ + (ssl << 3);
    const int ldsst = tid << 4;

    // fragment-read per-thread constants (swizzled slot; row&7 == c&7)
    const int sA = (wm * 64 + c) * 128;
    const int sB = (wn * 64 + c) * 128;
    const int swz0 = ((0 * 4 + quad) ^ (c & 7)) << 4;   // kk=0
    const int swz1 = ((1 * 4 + quad) ^ (c & 7)) << 4;   // kk=1

    f32x4 acc[4][4];
    #pragma unroll
    for (int i = 0; i < 4; i++)
        #pragma unroll
        for (int j = 0; j < 4; j++)
            acc[i][j] = (f32x4){0.f, 0.f, 0.f, 0.f};

    half8 a0[4][2], b0[4][2], a1[4][2], b1[4][2];

    // prologue: stage tiles 0,1; wait tile0 (oldest 8 of 16); read tile0 frags -> set0
    STAGE_T(0);
    STAGE_T(1);
    PH_WAIT(8); SBAR;
    LOADFRAGS(0, a0, b0);

    ITER(0, a0, b0, a1, b1, 1, 8);
    ITER(1, a1, b1, a0, b0, 1, 8);
    ITER(2, a0, b0, a1, b1, 1, 8);
    ITER(3, a1, b1, a0, b0, 1, 8);
    ITER(4, a0, b0, a1, b1, 1, 8);
    ITER(5, a1, b1, a0, b0, 1, 8);
    ITER(6, a0, b0, a1, b1, 0, 0);   // drains tile7 staging; loads tile7 frags -> set1
    WAITLGKM0; SCHED0;
    DOMFMA(a1, b1);                  // tile 7

    __syncthreads();   // GEMM done; reuse smem for reduction staging

    // per-lane epilogue: score s = wnorm[n] - 2*acc; packed-u64 argmin over (ni, c)
    const unsigned long long ID = (0xFF800000ull << 32) | 0x7FFFFFFFull;  // (+inf, IMAX)
    float wnl[4]; int cll[4];
    #pragma unroll
    for (int ni = 0; ni < 4; ni++) {
        int n = n0 + wn * 64 + ni * 16 + c;
        wnl[ni] = wnorm[n];
        cll[ni] = clabels[n];
    }

    unsigned long long* bq = (unsigned long long*)smem;           // [2][128]
    unsigned long long* cq = (unsigned long long*)(smem + 2048);  // [2][128]

    #pragma unroll
    for (int mi = 0; mi < 4; mi++) {
        #pragma unroll
        for (int r = 0; r < 4; r++) {
            int rowl = wm * 64 + mi * 16 + quad * 4 + r;   // 0..127 in block
            int lb = labels[m0 + rowl];
            unsigned long long bb = ID, cb = ID;
            #pragma unroll
            for (int ni = 0; ni < 4; ni++) {
                float s = fmaf(-2.f, acc[mi][ni][r], wnl[ni]);
                unsigned long long pk = packmin(s, n0 + wn * 64 + ni * 16 + c);
                bb = bb < pk ? bb : pk;
                if (cll[ni] == lb) cb = cb < pk ? cb : pk;
            }
            #pragma unroll
            for (int off = 1; off < 16; off <<= 1) {   // butterfly over c
                unsigned long long ob = __shfl_xor(bb, off, 64);
                bb = bb < ob ? bb : ob;
                unsigned long long oc = __shfl_xor(cb, off, 64);
                cb = cb < oc ? cb : oc;
            }
            if (c == 0) { bq[wn * 128 + rowl] = bb; cq[wn * 128 + rowl] = cb; }
        }
    }
    __syncthreads();
    {
        int which = tid >> 7, row = tid & 127;
        unsigned long long* q = which ? cq : bq;
        unsigned long long m = q[row];
        unsigned long long v = q[128 + row];
        m = m < v ? m : v;
        float vv; int n; unpackmin(m, &vv, &n);
        size_t pp = (size_t)(m0 + row) * NTP + ntile;
        if (which) { pcminv[pp] = vv; pcmini[pp] = n; }
        else       { pminv[pp]  = vv; pmini[pp]  = n; }
    }
}

// ---------------- reduce partials per row; emit bmu, sum(min_dists), som_errors ----------------
__global__ __launch_bounds__(128) void reduce_kernel(
    const float* __restrict__ A, const float* __restrict__ W,
    const float* __restrict__ crel,
    const float* __restrict__ pminv, const int* __restrict__ pmini,
    const float* __restrict__ pcminv, const int* __restrict__ pcmini,
    int* __restrict__ bmu, float* __restrict__ sum_min, float* __restrict__ out0)
{
    int b = blockIdx.x, t = threadIdx.x;
    __shared__ float sv[128]; __shared__ int si[128];
    __shared__ float scv[128]; __shared__ int sci[128];
    __shared__ float xs[128];
    __shared__ int   cbmu_s;

    size_t p = (size_t)b * NTP + t;
    sv[t] = pminv[p]; si[t] = pmini[p]; scv[t] = pcminv[p]; sci[t] = pcmini[p];

    float4 x4 = ((const float4*)(A + (size_t)b * D_))[t];
    xs[t] = x4.x*x4.x + x4.y*x4.y + x4.z*x4.z + x4.w*x4.w;
    __syncthreads();
    for (int s = 64; s > 0; s >>= 1) {
        if (t < s) {
            float v = sv[t+s]; int idx = si[t+s];
            if (v < sv[t] || (v == sv[t] && idx < si[t])) { sv[t] = v; si[t] = idx; }
            v = scv[t+s]; idx = sci[t+s];
            if (v < scv[t] || (v == scv[t] && idx < sci[t])) { scv[t] = v; sci[t] = idx; }
            xs[t] += xs[t+s];
        }
        __syncthreads();
    }
    if (t == 0) {
        bmu[b] = si[0];
        float md = xs[0] + sv[0];
        if (md < 0.f) md = 0.f;
        atomicAdd(&sum_min[b & 63], md);   // bucketed: avoids same-address serialization
        cbmu_s = sci[0];
    }
    __syncthreads();
    int cb = cbmu_s;
    float r = crel[cb] / 100.0f;
    float val = (r >= THR_) ? 1.0f : 0.0f;
    float sc = 0.01f * r * val;
    float4 w4 = ((const float4*)(W + (size_t)cb * D_))[t];
    float4 o;
    o.x = sc * (w4.x - x4.x); o.y = sc * (w4.y - x4.y);
    o.z = sc * (w4.z - x4.z); o.w = sc * (w4.w - x4.w);
    ((float4*)(out0 + (size_t)b * D_))[t] = o;
}

// ---------------- per-BMU accumulate: S[bmu] += A[b], count[bmu] += 1 ----------------
__global__ __launch_bounds__(512) void scatter1_kernel(
    const float* __restrict__ A, const int* __restrict__ bmu,
    float* S, float* count)
{
    int b = blockIdx.x, d = threadIdx.x;
    int bm = bmu[b];
    float x = A[(size_t)b * D_ + d];
    atomicAdd(&S[(size_t)bm * D_ + d], x);
    if (d == 0) atomicAdd(&count[bm], 1.0f);
}

// ---------------- denom via Chebyshev stencil over counts; fold sum_min buckets ----------------
__global__ __launch_bounds__(256) void denom_kernel(
    const float* __restrict__ count,
    const int* __restrict__ epoch_p, const int* __restrict__ maxep_p,
    float* __restrict__ denom, float* __restrict__ sum_min)
{
    int n = blockIdx.x * 256 + threadIdx.x;
    if (n >= N_) return;
    if (n == 0) {
        float s = 0.f;
        for (int i = 0; i < 64; i++) s += sum_min[i];
        sum_min[64] = s;
    }
    int ep = epoch_p[0], me = maxep_p[0];
    float progress = (me > 0) ? (float)(me - ep) / (float)me : 0.f;
    progress = fminf(fmaxf(progress, 0.f), 1.f);
    float p2 = progress * progress;
    int ctx = (int)(p2 * p2 * 2.0f);
    float lr = 0.05f + progress * 0.15f;

    int i = n / G_, j = n % G_;
    float s = 0.f;
    for (int di = -ctx; di <= ctx; di++) {
        int ia = i - di; if (ia < 0 || ia >= G_) continue;
        for (int dj = -ctx; dj <= ctx; dj++) {
            int jb = j - dj; if (jb < 0 || jb >= G_) continue;
            int ad = abs(di), aj = abs(dj);
            int cheb = ad > aj ? ad : aj;
            s += ldexpf(lr, -cheb) * count[jb * G_ + ia];
        }
    }
    denom[n] = s;
}

// ---------------- final: out1 = som + stencil(S) - som*denom (gated) ----------------
__global__ __launch_bounds__(256) void final_kernel(
    const float* __restrict__ som, const float* __restrict__ S,
    const float* __restrict__ denom, const float* __restrict__ sum_min,
    const int* __restrict__ epoch_p, const int* __restrict__ maxep_p,
    float* __restrict__ out1)
{
    size_t i4 = (size_t)blockIdx.x * 256 + threadIdx.x;
    if (i4 >= (size_t)N_ * D_ / 4) return;
    int n = (int)(i4 >> 7);          // 128 float4 per cell row
    int d4 = (int)(i4 & 127);
    float4 s = ((const float4*)som)[i4];
    bool gate = sum_min[64] > 1e-4f * (float)B_;   // mean(min_dists) > 1e-4
    float4 o = s;
    if (gate) {
        int ep = epoch_p[0], me = maxep_p[0];
        float progress = (me > 0) ? (float)(me - ep) / (float)me : 0.f;
        progress = fminf(fmaxf(progress, 0.f), 1.f);
        float p2 = progress * progress;
        int ctx = (int)(p2 * p2 * 2.0f);
        float lr = 0.05f + progress * 0.15f;

        int i = n / G_, j = n % G_;
        float4 nu = {0.f, 0.f, 0.f, 0.f};
        for (int di = -ctx; di <= ctx; di++) {
            int ia = i - di; if (ia < 0 || ia >= G_) continue;
            for (int dj = -ctx; dj <= ctx; dj++) {
                int jb = j - dj; if (jb < 0 || jb >= G_) continue;
                int ad = abs(di), aj = abs(dj);
                int cheb = ad > aj ? ad : aj;
                float coef = ldexpf(lr, -cheb);
                float4 t4 = ((const float4*)S)[(size_t)(jb * G_ + ia) * 128 + d4];
                nu.x += coef * t4.x; nu.y += coef * t4.y;
                nu.z += coef * t4.z; nu.w += coef * t4.w;
            }
        }
        float dn = denom[n];
        o.x = s.x + nu.x - s.x * dn;
        o.y = s.y + nu.y - s.y * dn;
        o.z = s.z + nu.z - s.z * dn;
        o.w = s.w + nu.w - s.w * dn;
    }
    ((float4*)out1)[i4] = o;
}

extern "C" void kernel_launch(void* const* d_in, const int* in_sizes, int n_in,
                              void* d_out, int out_size, void* d_ws, size_t ws_size,
                              hipStream_t stream) {
    const float* A   = (const float*)d_in[0];   // activations [B][D]
    const int*   lab = (const int*)d_in[1];     // labels [B]
    const float* W   = (const float*)d_in[2];   // som_vectors [G*G][D]
    const int*   cl  = (const int*)d_in[3];     // cell_labels [G*G]
    const float* cr  = (const float*)d_in[4];   // cell_reliability [G*G]
    const int*   ep  = (const int*)d_in[5];     // epoch
    const int*   me  = (const int*)d_in[6];     // max_epochs

    float* out0 = (float*)d_out;                // som_errors [B][D]
    float* out1 = out0 + (size_t)B_ * D_;       // new_som [G*G][D]

    const size_t MB = 1024 * 1024;
    uint8_t* w = (uint8_t*)d_ws;
    // phase 1 (score): f16-hi buffers occupy [0, 20 MB)
    _Float16* Ahi  = (_Float16*)(w);                    //  4 MB
    _Float16* Whi  = (_Float16*)(w + 4 * MB);           // 16 MB
    // phase 2 (update): S aliases the dead split region [0, 32 MB)
    float* S       = (float*)(w);                       // 32 MB (after score)
    float* pminv   = (float*)(w + 32 * MB);             //  2 MB
    int*   pmini   = (int*)  (w + 34 * MB);             //  2 MB
    float* pcminv  = (float*)(w + 36 * MB);             //  2 MB
    int*   pcmini  = (int*)  (w + 38 * MB);             //  2 MB
    float* wnorm   = (float*)(w + 40 * MB);             // 64 KB
    float* denom   = (float*)(w + 40 * MB + 64 * 1024); // 64 KB
    float* count   = (float*)(w + 40 * MB + 128 * 1024);// 64 KB
    int*   bmu     = (int*)  (w + 40 * MB + 192 * 1024);// 64 KB
    float* sum_min = (float*)(w + 40 * MB + 256 * 1024);// 65 floats: 64 buckets + total

    hipMemsetAsync(sum_min, 0, 65 * sizeof(float), stream);

    split_hi_kernel<<<(B_ * D_ / 4 + 255) / 256, 256, 0, stream>>>(A, Ahi, B_ * D_ / 4);
    prep_w_kernel<<<N_ / 4, 256, 0, stream>>>(W, Whi, wnorm);

    score_mfma_kernel<<<dim3((B_ / 128) * (N_ / 128)), 256, 0, stream>>>(
        Ahi, Whi, wnorm, lab, cl, pminv, pmini, pcminv, pcmini);

    reduce_kernel<<<B_, 128, 0, stream>>>(A, W, cr, pminv, pmini, pcminv, pcmini,
                                          bmu, sum_min, out0);

    // f16 buffers are dead now; reuse as S (stream-ordered)
    hipMemsetAsync(S, 0, (size_t)N_ * D_ * sizeof(float), stream);
    hipMemsetAsync(count, 0, (size_t)N_ * sizeof(float), stream);

    scatter1_kernel<<<B_, 512, 0, stream>>>(A, bmu, S, count);

    denom_kernel<<<(N_ + 255) / 256, 256, 0, stream>>>(count, ep, me, denom, sum_min);

    final_kernel<<<(N_ * D_ / 4 + 255) / 256, 256, 0, stream>>>(
        W, S, denom, sum_min, ep, me, out1);
}

// Round 7
// 275.796 us; speedup vs baseline: 1.2140x; 1.2140x over previous
//
#include <hip/hip_runtime.h>
#include <math.h>

#define B_ 4096
#define D_ 512
#define G_ 128
#define N_ (G_*G_)        // 16384
#define NTP 64            // number of 256-wide n tiles (partials per row)
#define THR_ 0.95f
#define IMAX_ 0x7FFFFFFF

typedef float f32x4 __attribute__((ext_vector_type(4)));
typedef _Float16 half8 __attribute__((ext_vector_type(8)));

// ---------------- split fp32 -> f16 hi only ----------------
__global__ __launch_bounds__(256) void split_hi_kernel(const float* __restrict__ src,
                                                       _Float16* __restrict__ hi, int n4) {
    int i = blockIdx.x * 256 + threadIdx.x;
    if (i >= n4) return;
    float4 v = ((const float4*)src)[i];
    float vv[4] = {v.x, v.y, v.z, v.w};
    union { _Float16 h[4]; uint64_t u64; } H;
    #pragma unroll
    for (int j = 0; j < 4; j++) H.h[j] = (_Float16)vv[j];
    ((uint64_t*)hi)[i] = H.u64;
}

// ---------------- fused W split(hi) + wnorm; 4 rows per 256-thread block ----------------
__global__ __launch_bounds__(256) void prep_w_kernel(const float* __restrict__ W,
                                                     _Float16* __restrict__ hi,
                                                     float* __restrict__ wnorm) {
    int n = blockIdx.x * 4 + (threadIdx.x >> 6);
    int t = threadIdx.x & 63;
    const float* row = W + (size_t)n * D_;
    float4 a = ((const float4*)row)[t];
    float4 b = ((const float4*)row)[t + 64];
    float av[4] = {a.x, a.y, a.z, a.w}, bv[4] = {b.x, b.y, b.z, b.w};
    union { _Float16 h[4]; uint64_t u64; } Ha, Hb;
    #pragma unroll
    for (int j = 0; j < 4; j++) { Ha.h[j] = (_Float16)av[j]; Hb.h[j] = (_Float16)bv[j]; }
    ((uint64_t*)(hi + (size_t)n * D_))[t]       = Ha.u64;
    ((uint64_t*)(hi + (size_t)n * D_ + 256))[t] = Hb.u64;
    float s = a.x*a.x + a.y*a.y + a.z*a.z + a.w*a.w
            + b.x*b.x + b.y*b.y + b.z*b.z + b.w*b.w;
    #pragma unroll
    for (int off = 32; off > 0; off >>= 1) s += __shfl_down(s, off, 64);
    if (t == 0) wnorm[n] = s;
}

// ---------------- packed (value,index) helpers for argmin ----------------
__device__ __forceinline__ unsigned long long packmin(float v, int n) {
    unsigned u = __float_as_uint(v);
    u ^= (u & 0x80000000u) ? 0xFFFFFFFFu : 0x80000000u;
    return ((unsigned long long)u << 32) | (unsigned)n;
}
__device__ __forceinline__ void unpackmin(unsigned long long pkt, float* v, int* n) {
    unsigned u = (unsigned)(pkt >> 32);
    u = (u & 0x80000000u) ? (u ^ 0x80000000u) : ~u;
    *v = __uint_as_float(u);
    *n = (int)(unsigned)pkt;
}

// ---------------- MFMA score GEMM: 256x256 tile, 8 waves, 8-tile 4-phase pipeline ----------------
// score = wnorm[n] - 2 * dot_f16(x, w)  (x_norm added per-row later; argmin-invariant).
// GEMM loop = round-4 schedule (verified bit-exact, 132us). Round-6 change: the epilogue.
// Old epilogue: u64 shfl butterfly = ~1024 ds_bpermute-instr/thread ~= 20us/CU of LDS pipe.
// New: LDS table [256][64] u64 (exactly 128KB smem reuse); each thread writes its 32
// candidates (slot XOR row&15 caps conflicts at 4-way), 256 threads min-reduce one row
// each (64 ds_read_b64). Class-candidates stashed in 64 VGPRs for a second pass.
// Candidate set + u64-min semantics identical -> argmin/tie-breaks unchanged.

#define PH_WAIT_(N) asm volatile("s_waitcnt vmcnt(" #N ")" ::: "memory")
#define PH_WAIT(N) PH_WAIT_(N)
#define WAITLGKM0 asm volatile("s_waitcnt lgkmcnt(0)" ::: "memory")
#define SBAR __builtin_amdgcn_s_barrier()
#define SCHED0 __builtin_amdgcn_sched_barrier(0)
#define PRIO1 __builtin_amdgcn_s_setprio(1)
#define PRIO0 __builtin_amdgcn_s_setprio(0)

// stage one 16KB half-tile (128 rows x 64 k f16): 2 global_load_lds x 16B per thread
#define STAGE_HALF(GBASE, LOFF, TAU, H) do { \
    __builtin_amdgcn_global_load_lds( \
        (const __attribute__((address_space(1))) void*)((GBASE) + (size_t)(H) * (128 * D_) + (TAU) * 64 + srcoff0), \
        (__attribute__((address_space(3))) void*)(smem + (LOFF) + (((TAU) & 1) << 15) + ((H) << 14) + ldsoff0), 16, 0, 0); \
    __builtin_amdgcn_global_load_lds( \
        (const __attribute__((address_space(1))) void*)((GBASE) + (size_t)(H) * (128 * D_) + (TAU) * 64 + srcoff1), \
        (__attribute__((address_space(3))) void*)(smem + (LOFF) + (((TAU) & 1) << 15) + ((H) << 14) + ldsoff1), 16, 0, 0); \
} while (0)

// S1: stage Ahi[TAU+1] in P1.  S3: stage Blo[TAU+2] in P3.  S4: stage Alo/Bhi[TAU+2] in P4.
// DO_W/VM4: counted wait in P4 (after stages) covering tile TAU+1 readiness.
#define TILE(TAU, S1, S3, S4, DO_W, VM4) do { \
    half8 af[4][2], bl[2][2], bh[2][2]; \
    /* P1: ds A rows 0-63 (8) + B rows 0-31 (4); stage Ahi[TAU+1]; MFMA mi0-3 x ni0-1 */ \
    _Pragma("unroll") for (int mi = 0; mi < 4; mi++) { \
        af[mi][0] = *(const half8*)(smem + (((TAU) & 1) << 15) + sA + mi * 2048 + swz0); \
        af[mi][1] = *(const half8*)(smem + (((TAU) & 1) << 15) + sA + mi * 2048 + swz1); } \
    _Pragma("unroll") for (int ni = 0; ni < 2; ni++) { \
        bl[ni][0] = *(const half8*)(smem + 65536 + (((TAU) & 1) << 15) + sB + ni * 2048 + swz0); \
        bl[ni][1] = *(const half8*)(smem + 65536 + (((TAU) & 1) << 15) + sB + ni * 2048 + swz1); } \
    if (S1) STAGE_HALF(Abase, 0, (TAU) + 1, 1); \
    SBAR; WAITLGKM0; SCHED0; PRIO1; \
    _Pragma("unroll") for (int mi = 0; mi < 4; mi++) \
      _Pragma("unroll") for (int ni = 0; ni < 2; ni++) { \
        acc[mi][ni] = __builtin_amdgcn_mfma_f32_16x16x32_f16(af[mi][0], bl[ni][0], acc[mi][ni], 0, 0, 0); \
        acc[mi][ni] = __builtin_amdgcn_mfma_f32_16x16x32_f16(af[mi][1], bl[ni][1], acc[mi][ni], 0, 0, 0); } \
    PRIO0; SCHED0; SBAR; \
    /* P2: ds B rows 32-63 (4); MFMA mi0-3 x ni2-3.  (B reads of this tile end here.) */ \
    _Pragma("unroll") for (int ni = 0; ni < 2; ni++) { \
        bh[ni][0] = *(const half8*)(smem + 65536 + (((TAU) & 1) << 15) + sB + (ni + 2) * 2048 + swz0); \
        bh[ni][1] = *(const half8*)(smem + 65536 + (((TAU) & 1) << 15) + sB + (ni + 2) * 2048 + swz1); } \
    SBAR; WAITLGKM0; SCHED0; PRIO1; \
    _Pragma("unroll") for (int mi = 0; mi < 4; mi++) \
      _Pragma("unroll") for (int ni = 0; ni < 2; ni++) { \
        acc[mi][ni + 2] = __builtin_amdgcn_mfma_f32_16x16x32_f16(af[mi][0], bh[ni][0], acc[mi][ni + 2], 0, 0, 0); \
        acc[mi][ni + 2] = __builtin_amdgcn_mfma_f32_16x16x32_f16(af[mi][1], bh[ni][1], acc[mi][ni + 2], 0, 0, 0); } \
    PRIO0; SCHED0; SBAR; \
    /* P3: ds A rows 64-127 (8); stage Blo[TAU+2]; MFMA mi4-7 x ni2-3.  (A reads end here.) */ \
    _Pragma("unroll") for (int mi = 0; mi < 4; mi++) { \
        af[mi][0] = *(const half8*)(smem + (((TAU) & 1) << 15) + sA + (mi + 4) * 2048 + swz0); \
        af[mi][1] = *(const half8*)(smem + (((TAU) & 1) << 15) + sA + (mi + 4) * 2048 + swz1); } \
    if (S3) STAGE_HALF(Wbase, 65536, (TAU) + 2, 0); \
    SBAR; WAITLGKM0; SCHED0; PRIO1; \
    _Pragma("unroll") for (int mi = 0; mi < 4; mi++) \
      _Pragma("unroll") for (int ni = 0; ni < 2; ni++) { \
        acc[mi + 4][ni + 2] = __builtin_amdgcn_mfma_f32_16x16x32_f16(af[mi][0], bh[ni][0], acc[mi + 4][ni + 2], 0, 0, 0); \
        acc[mi + 4][ni + 2] = __builtin_amdgcn_mfma_f32_16x16x32_f16(af[mi][1], bh[ni][1], acc[mi + 4][ni + 2], 0, 0, 0); } \
    PRIO0; SCHED0; SBAR; \
    /* P4: stage Alo[TAU+2] + Bhi[TAU+2]; counted wait; MFMA mi4-7 x ni0-1 (regs only) */ \
    if (S4) { STAGE_HALF(Abase, 0, (TAU) + 2, 0); STAGE_HALF(Wbase, 65536, (TAU) + 2, 1); } \
    if (DO_W) PH_WAIT(VM4); \
    SBAR; PRIO1; \
    _Pragma("unroll") for (int mi = 0; mi < 4; mi++) \
      _Pragma("unroll") for (int ni = 0; ni < 2; ni++) { \
        acc[mi + 4][ni] = __builtin_amdgcn_mfma_f32_16x16x32_f16(af[mi][0], bl[ni][0], acc[mi + 4][ni], 0, 0, 0); \
        acc[mi + 4][ni] = __builtin_amdgcn_mfma_f32_16x16x32_f16(af[mi][1], bl[ni][1], acc[mi + 4][ni], 0, 0, 0); } \
    PRIO0; SCHED0; SBAR; \
} while (0)

__global__ __launch_bounds__(512, 2) void score_mfma_kernel(
    const _Float16* __restrict__ Ah, const _Float16* __restrict__ Wh,
    const float* __restrict__ wnorm,
    const int* __restrict__ labels, const int* __restrict__ clabels,
    float* __restrict__ pminv, int* __restrict__ pmini,
    float* __restrict__ pcminv, int* __restrict__ pcmini)
{
    __shared__ __align__(16) char smem[131072];  // A: 2x32KB @0, B: 2x32KB @64KB

    const int tid  = threadIdx.x;
    const int lane = tid & 63;
    const int wave = tid >> 6;
    const int wm = wave >> 2, wn = wave & 3;     // 2M x 4N wave grid; 128x64 per wave
    const int c = lane & 15, quad = lane >> 4;

    // XCD-chunked swizzle: 1024 blocks, 8 ntiles/XCD chunk (2MB W, L2-resident) x 16 mtiles
    const int o = blockIdx.x;
    const int xcd = o & 7, idx = o >> 3;
    const int ntile = (xcd << 3) | (idx & 7);
    const int mtile = idx >> 3;
    const int m0 = mtile * 256, n0 = ntile * 256;

    const _Float16* Abase = Ah + (size_t)m0 * D_;
    const _Float16* Wbase = Wh + (size_t)n0 * D_;

    // staging per-thread constants (pre-swizzled global source, linear LDS dest)
    const int i0 = tid, i1 = 512 + tid;
    const int rl0 = i0 >> 3, sl0 = i0 & 7, rl1 = i1 >> 3, sl1 = i1 & 7;
    const size_t srcoff0 = (size_t)rl0 * D_ + ((sl0 ^ (rl0 & 7)) << 3);
    const size_t srcoff1 = (size_t)rl1 * D_ + ((sl1 ^ (rl1 & 7)) << 3);
    const int ldsoff0 = i0 << 4, ldsoff1 = i1 << 4;

    // fragment-read per-thread constants (swizzled slot; row&7 == c&7)
    const int sA = (wm * 128 + c) * 128;
    const int sB = (wn * 64 + c) * 128;
    const int swz0 = ((0 * 4 + quad) ^ (c & 7)) << 4;   // kk=0
    const int swz1 = ((1 * 4 + quad) ^ (c & 7)) << 4;   // kk=1

    f32x4 acc[8][4];
    #pragma unroll
    for (int i = 0; i < 8; i++)
        #pragma unroll
        for (int j = 0; j < 4; j++)
            acc[i][j] = (f32x4){0.f, 0.f, 0.f, 0.f};

    // prologue: issue Alo0, Blo0, Bhi0, Ahi0, Alo1, Blo1, Bhi1 (14 loads);
    // wait vmcnt(6): all of tile0 (oldest 8 loads) complete for this wave; barrier -> global
    STAGE_HALF(Abase, 0, 0, 0);
    STAGE_HALF(Wbase, 65536, 0, 0);
    STAGE_HALF(Wbase, 65536, 0, 1);
    STAGE_HALF(Abase, 0, 0, 1);
    STAGE_HALF(Abase, 0, 1, 0);
    STAGE_HALF(Wbase, 65536, 1, 0);
    STAGE_HALF(Wbase, 65536, 1, 1);
    PH_WAIT(6); SBAR;

    TILE(0, 1, 1, 1, 1, 6);
    TILE(1, 1, 1, 1, 1, 6);
    TILE(2, 1, 1, 1, 1, 6);
    TILE(3, 1, 1, 1, 1, 6);
    TILE(4, 1, 1, 1, 1, 6);
    TILE(5, 1, 1, 1, 1, 6);
    TILE(6, 1, 0, 0, 1, 0);   // stages Ahi7 (last); drains all -> tile7 ready
    TILE(7, 0, 0, 0, 0, 0);

    __syncthreads();   // GEMM done; reuse smem as [256][64] u64 candidate table

    // per-lane epilogue: score s = wnorm[n] - 2*acc; LDS-table argmin over (ni, wn, c)
    const unsigned long long ID = (0xFF800000ull << 32) | 0x7FFFFFFFull;  // (+inf, IMAX)
    float wnl[4]; int cll[4];
    #pragma unroll
    for (int ni = 0; ni < 4; ni++) {
        int n = n0 + wn * 64 + ni * 16 + c;
        wnl[ni] = wnorm[n];
        cll[ni] = clabels[n];
    }

    unsigned long long (*tbl)[64] = (unsigned long long (*)[64])smem;  // 128KB exactly
    unsigned long long cbst[8][4];

    #pragma unroll
    for (int mi = 0; mi < 8; mi++) {
        #pragma unroll
        for (int r = 0; r < 4; r++) {
            int rowl = wm * 128 + mi * 16 + quad * 4 + r;   // 0..255 in block
            int lb = labels[m0 + rowl];
            unsigned long long bb = ID, cb = ID;
            #pragma unroll
            for (int ni = 0; ni < 4; ni++) {
                float s = fmaf(-2.f, acc[mi][ni][r], wnl[ni]);
                unsigned long long pk = packmin(s, n0 + wn * 64 + ni * 16 + c);
                bb = bb < pk ? bb : pk;
                if (cll[ni] == lb) cb = cb < pk ? cb : pk;
            }
            tbl[rowl][(wn * 16 + c) ^ (rowl & 15)] = bb;   // XOR slot: caps conflicts 4-way
            cbst[mi][r] = cb;
        }
    }
    __syncthreads();
    if (tid < 256) {
        int row = tid;
        unsigned long long m = ID;
        #pragma unroll
        for (int j = 0; j < 64; j++) {
            unsigned long long v = tbl[row][j ^ (row & 15)];
            m = m < v ? m : v;
        }
        float v; int n; unpackmin(m, &v, &n);
        size_t pp = (size_t)(m0 + row) * NTP + ntile;
        pminv[pp] = v; pmini[pp] = n;
    }
    __syncthreads();
    #pragma unroll
    for (int mi = 0; mi < 8; mi++)
        #pragma unroll
        for (int r = 0; r < 4; r++) {
            int rowl = wm * 128 + mi * 16 + quad * 4 + r;
            tbl[rowl][(wn * 16 + c) ^ (rowl & 15)] = cbst[mi][r];
        }
    __syncthreads();
    if (tid < 256) {
        int row = tid;
        unsigned long long m = ID;
        #pragma unroll
        for (int j = 0; j < 64; j++) {
            unsigned long long v = tbl[row][j ^ (row & 15)];
            m = m < v ? m : v;
        }
        float v; int n; unpackmin(m, &v, &n);
        size_t pp = (size_t)(m0 + row) * NTP + ntile;
        pcminv[pp] = v; pcmini[pp] = n;
    }
}

// ---------------- reduce partials per row; emit bmu, sum(min_dists), som_errors ----------------
// Round 6: also zeroes S (4 rows/block) and count (4 cells/block), replacing 2 memsets.
__global__ __launch_bounds__(128) void reduce_kernel(
    const float* __restrict__ A, const float* __restrict__ W,
    const float* __restrict__ crel,
    const float* __restrict__ pminv, const int* __restrict__ pmini,
    const float* __restrict__ pcminv, const int* __restrict__ pcmini,
    int* __restrict__ bmu, float* __restrict__ sum_min, float* __restrict__ out0,
    float* __restrict__ S, float* __restrict__ count)
{
    int b = blockIdx.x, t = threadIdx.x;
    __shared__ float sv[128]; __shared__ int si[128];
    __shared__ float scv[128]; __shared__ int sci[128];
    __shared__ float xs[128];
    __shared__ int   cbmu_s;

    // zero S rows [4b,4b+4) and count[4b..4b+4)  (S aliases the dead f16 buffers)
    {
        float4 z = {0.f, 0.f, 0.f, 0.f};
        #pragma unroll
        for (int k = 0; k < 4; k++)
            ((float4*)S)[((size_t)(b * 4 + k)) * 128 + t] = z;
        if (t < 4) count[b * 4 + t] = 0.f;
    }

    if (t < NTP) {
        size_t p = (size_t)b * NTP + t;
        sv[t] = pminv[p]; si[t] = pmini[p]; scv[t] = pcminv[p]; sci[t] = pcmini[p];
    } else {
        sv[t] = INFINITY; si[t] = IMAX_; scv[t] = INFINITY; sci[t] = IMAX_;
    }

    float4 x4 = ((const float4*)(A + (size_t)b * D_))[t];
    xs[t] = x4.x*x4.x + x4.y*x4.y + x4.z*x4.z + x4.w*x4.w;
    __syncthreads();
    for (int s = 64; s > 0; s >>= 1) {
        if (t < s) {
            float v = sv[t+s]; int idx = si[t+s];
            if (v < sv[t] || (v == sv[t] && idx < si[t])) { sv[t] = v; si[t] = idx; }
            v = scv[t+s]; idx = sci[t+s];
            if (v < scv[t] || (v == scv[t] && idx < sci[t])) { scv[t] = v; sci[t] = idx; }
            xs[t] += xs[t+s];
        }
        __syncthreads();
    }
    if (t == 0) {
        bmu[b] = si[0];
        float md = xs[0] + sv[0];
        if (md < 0.f) md = 0.f;
        atomicAdd(&sum_min[b & 63], md);   // bucketed: avoids same-address serialization
        cbmu_s = sci[0];
    }
    __syncthreads();
    int cb = cbmu_s;
    float r = crel[cb] / 100.0f;
    float val = (r >= THR_) ? 1.0f : 0.0f;
    float sc = 0.01f * r * val;
    float4 w4 = ((const float4*)(W + (size_t)cb * D_))[t];
    float4 o;
    o.x = sc * (w4.x - x4.x); o.y = sc * (w4.y - x4.y);
    o.z = sc * (w4.z - x4.z); o.w = sc * (w4.w - x4.w);
    ((float4*)(out0 + (size_t)b * D_))[t] = o;
}

// ---------------- per-BMU accumulate: S[bmu] += A[b], count[bmu] += 1; fold gate ----------------
__global__ __launch_bounds__(512) void scatter1_kernel(
    const float* __restrict__ A, const int* __restrict__ bmu,
    float* S, float* count, float* __restrict__ sum_min)
{
    int b = blockIdx.x, d = threadIdx.x;
    if (b == 0 && d == 0) {          // buckets final (written by reduce, prior kernel)
        float s = 0.f;
        for (int i = 0; i < 64; i++) s += sum_min[i];
        sum_min[64] = s;
    }
    int bm = bmu[b];
    float x = A[(size_t)b * D_ + d];
    atomicAdd(&S[(size_t)bm * D_ + d], x);
    if (d == 0) atomicAdd(&count[bm], 1.0f);
}

// ---------------- final: out1 = som + stencil(S) - som*denom (gated); denom inlined ----------------
__global__ __launch_bounds__(256) void final_kernel(
    const float* __restrict__ som, const float* __restrict__ S,
    const float* __restrict__ count, const float* __restrict__ sum_min,
    const int* __restrict__ epoch_p, const int* __restrict__ maxep_p,
    float* __restrict__ out1)
{
    size_t i4 = (size_t)blockIdx.x * 256 + threadIdx.x;
    if (i4 >= (size_t)N_ * D_ / 4) return;
    int n = (int)(i4 >> 7);          // 128 float4 per cell row
    int d4 = (int)(i4 & 127);
    float4 s = ((const float4*)som)[i4];
    bool gate = sum_min[64] > 1e-4f * (float)B_;   // mean(min_dists) > 1e-4
    float4 o = s;
    if (gate) {
        int ep = epoch_p[0], me = maxep_p[0];
        float progress = (me > 0) ? (float)(me - ep) / (float)me : 0.f;
        progress = fminf(fmaxf(progress, 0.f), 1.f);
        float p2 = progress * progress;
        int ctx = (int)(p2 * p2 * 2.0f);
        float lr = 0.05f + progress * 0.15f;

        int i = n / G_, j = n % G_;
        float4 nu = {0.f, 0.f, 0.f, 0.f};
        float dn = 0.f;
        for (int di = -ctx; di <= ctx; di++) {
            int ia = i - di; if (ia < 0 || ia >= G_) continue;
            for (int dj = -ctx; dj <= ctx; dj++) {
                int jb = j - dj; if (jb < 0 || jb >= G_) continue;
                int ad = abs(di), aj = abs(dj);
                int cheb = ad > aj ? ad : aj;
                float coef = ldexpf(lr, -cheb);
                float4 t4 = ((const float4*)S)[(size_t)(jb * G_ + ia) * 128 + d4];
                nu.x += coef * t4.x; nu.y += coef * t4.y;
                nu.z += coef * t4.z; nu.w += coef * t4.w;
                dn += coef * count[jb * G_ + ia];
            }
        }
        o.x = s.x + nu.x - s.x * dn;
        o.y = s.y + nu.y - s.y * dn;
        o.z = s.z + nu.z - s.z * dn;
        o.w = s.w + nu.w - s.w * dn;
    }
    ((float4*)out1)[i4] = o;
}

extern "C" void kernel_launch(void* const* d_in, const int* in_sizes, int n_in,
                              void* d_out, int out_size, void* d_ws, size_t ws_size,
                              hipStream_t stream) {
    const float* A   = (const float*)d_in[0];   // activations [B][D]
    const int*   lab = (const int*)d_in[1];     // labels [B]
    const float* W   = (const float*)d_in[2];   // som_vectors [G*G][D]
    const int*   cl  = (const int*)d_in[3];     // cell_labels [G*G]
    const float* cr  = (const float*)d_in[4];   // cell_reliability [G*G]
    const int*   ep  = (const int*)d_in[5];     // epoch
    const int*   me  = (const int*)d_in[6];     // max_epochs

    float* out0 = (float*)d_out;                // som_errors [B][D]
    float* out1 = out0 + (size_t)B_ * D_;       // new_som [G*G][D]

    const size_t MB = 1024 * 1024;
    uint8_t* w = (uint8_t*)d_ws;
    // phase 1 (score): f16-hi buffers occupy [0, 20 MB)
    _Float16* Ahi  = (_Float16*)(w);                    //  4 MB
    _Float16* Whi  = (_Float16*)(w + 4 * MB);           // 16 MB
    // phase 2 (update): S aliases the dead split region [0, 32 MB)
    float* S       = (float*)(w);                       // 32 MB (after score)
    float* pminv   = (float*)(w + 32 * MB);             //  1 MB used
    int*   pmini   = (int*)  (w + 34 * MB);             //  1 MB used
    float* pcminv  = (float*)(w + 36 * MB);             //  1 MB used
    int*   pcmini  = (int*)  (w + 38 * MB);             //  1 MB used
    float* wnorm   = (float*)(w + 40 * MB);             // 64 KB
    float* count   = (float*)(w + 40 * MB + 128 * 1024);// 64 KB
    int*   bmu     = (int*)  (w + 40 * MB + 192 * 1024);// 64 KB
    float* sum_min = (float*)(w + 40 * MB + 256 * 1024);// 65 floats: 64 buckets + total

    hipMemsetAsync(sum_min, 0, 65 * sizeof(float), stream);

    split_hi_kernel<<<(B_ * D_ / 4 + 255) / 256, 256, 0, stream>>>(A, Ahi, B_ * D_ / 4);
    prep_w_kernel<<<N_ / 4, 256, 0, stream>>>(W, Whi, wnorm);

    score_mfma_kernel<<<dim3((B_ / 256) * (N_ / 256)), 512, 0, stream>>>(
        Ahi, Whi, wnorm, lab, cl, pminv, pmini, pcminv, pcmini);

    // reduce also zeroes S (aliases dead f16 buffers) + count — stream-ordered
    reduce_kernel<<<B_, 128, 0, stream>>>(A, W, cr, pminv, pmini, pcminv, pcmini,
                                          bmu, sum_min, out0, S, count);

    scatter1_kernel<<<B_, 512, 0, stream>>>(A, bmu, S, count, sum_min);

    final_kernel<<<(N_ * D_ / 4 + 255) / 256, 256, 0, stream>>>(
        W, S, count, sum_min, ep, me, out1);
}